// Round 9
// baseline (166.262 us; speedup 1.0000x reference)
//
#include <hip/hip_runtime.h>

typedef __fp16 f16x2 __attribute__((ext_vector_type(2)));

#define Dm 128
#define Bn 16
#define VOX (Dm * Dm * Dm)
#define NT 256
#define WR 10            // words per halo row (20 halves: x[w0-2 .. w0+17])
#define SLAB 320         // 32 rows x 10 words per wave (rows 0..29 used)

__device__ __forceinline__ int iclamp(int v, int lo, int hi) {
  return v < lo ? lo : (v > hi ? hi : v);
}
__device__ __forceinline__ f16x2 pkrtz(float lo, float hi) {
  return __builtin_amdgcn_cvt_pkrtz(lo, hi);
}
__device__ __forceinline__ float pkbits(float lo, float hi) {
  return __builtin_bit_cast(float, __builtin_amdgcn_cvt_pkrtz(lo, hi));
}
__device__ __forceinline__ f16x2 asf16x2(float w) {
  return __builtin_bit_cast(f16x2, w);
}
// midpair(P, Q) = (Q.hi, P.lo)
__device__ __forceinline__ f16x2 midpair(f16x2 P, f16x2 Q) {
  unsigned r = __builtin_amdgcn_perm(__builtin_bit_cast(unsigned, P),
                                     __builtin_bit_cast(unsigned, Q),
                                     0x05040302u);
  return __builtin_bit_cast(f16x2, r);
}

// W transposed (wpkT[t*27+o] = W[o][t]) + bias, duplicated-half f16x2.
extern "C" __global__ void packW(const float* __restrict__ Wf,
                                 const float* __restrict__ bfp,
                                 float* __restrict__ wpk) {
  int i = threadIdx.x;
  if (i < 729) {
    int o = i / 27, t = i - o * 27;
    float v = Wf[i];
    wpk[t * 27 + o] = pkbits(v, v);
  } else if (i < 756) {
    float b = bfp[i - 729];
    wpk[i] = pkbits(b, b);
  }
}

// Wave-private tiles: each wave owns one z-slice (8y x 16w), stages its own
// 3z x 10y x 20w halo. ZERO barriers -> waves are independent streams; their
// memory stalls interleave on the SIMD instead of convoying at __syncthreads.
extern "C" __global__ void __launch_bounds__(NT, 8)   // force VGPR<=64 -> 8 blk/CU
fused3d(const float* __restrict__ img, const float* __restrict__ x,
        const float* __restrict__ wpk, float* __restrict__ out)
{
  __shared__ float sImg[4][SLAB];   // per-wave private regions, 10.2 KiB total
  __shared__ float sXw[4][SLAB];

  const int tid  = threadIdx.x;
  const int lane = tid & 63;
  const int wv   = tid >> 6;       // wave id == z offset within block tile
  const int tx   = lane & 7;       // w-pair 0..7
  const int ty   = lane >> 3;      // h 0..7

  // T1 XCD swizzle: contiguous slab of 512 spatial tiles per XCD
  const int bid = blockIdx.x;
  const int s  = (bid & 7) * 512 + (bid >> 3);
  const int bx = s & 7, by = (s >> 3) & 15, bz = s >> 7;
  const int w0 = bx * 16, h0 = by * 8, d0 = bz * 4;

  // ---- staging map: word i = 64k+lane; row r=i/10 (zz=r/10, yy=r%10),
  // col c=i%10 -> aligned float2 at x[gd, gh, w0-2+2c]. Clamped; rows 30/31 pad.
  int off[5];
  float mk0[5], mk1[5];            // img zero-pad masks (conv SAME)
#pragma unroll
  for (int k = 0; k < 5; ++k) {
    int i  = 64 * k + lane;
    int r  = i / WR;
    int c  = i - r * WR;
    int zz = r / 10;
    int yy = r - zz * 10;
    int gdo = d0 + wv + zz - 1;
    int gho = h0 + yy - 1;
    int gwo = w0 - 2 + 2 * c;
    int gd = iclamp(gdo, 0, Dm - 1);
    int gh = iclamp(gho, 0, Dm - 1);
    int gw = iclamp(gwo, 0, Dm - 2);        // even bounds keep 8B alignment
    off[k] = (gd * Dm + gh) * Dm + gw;
    bool rk = ((unsigned)gdo < Dm) & ((unsigned)gho < Dm);
    mk0[k] = (rk & ((unsigned)gwo < Dm))       ? 1.f : 0.f;
    mk1[k] = (rk & ((unsigned)(gwo + 1) < Dm)) ? 1.f : 0.f;
  }

  float* simg = sImg[wv];
  float* sxw  = sXw[wv];

  // ---- stage img (zero-masked) + issue x batch 0; NO barrier (wave-private)
#pragma unroll
  for (int k = 0; k < 5; ++k) {
    float2 v = *(const float2*)(img + off[k]);
    simg[64 * k + lane] = pkbits(v.x * mk0[k], v.y * mk1[k]);
  }
  float2 nx[5];
#pragma unroll
  for (int k = 0; k < 5; ++k)
    nx[k] = *(const float2*)(x + off[k]);

  // ---- K-gen: single pass, packed fp16; W rows contiguous (wpkT s_loads).
  // K-gen (~1600cy) covers batch-0 load latency.
  f16x2 K2[27];
#pragma unroll
  for (int o = 0; o < 27; ++o) K2[o] = asf16x2(wpk[729 + o]);
#pragma unroll
  for (int rr = 0; rr < 9; ++rr) {
    const int idx = ((rr / 3) * 10 + ty + (rr % 3)) * WR + tx;
    f16x2 a2 = asf16x2(simg[idx]);
    f16x2 b2 = asf16x2(simg[idx + 1]);
    f16x2 c2 = asf16x2(simg[idx + 2]);
    f16x2 h01 = midpair(b2, a2);   // (x[w-1], x[w])
    f16x2 h12 = b2;                // (x[w],   x[w+1])
    f16x2 h23 = midpair(c2, b2);   // (x[w+1], x[w+2])
    const float* wA = wpk + (rr * 3 + 0) * 27;
    const float* wB = wpk + (rr * 3 + 1) * 27;
    const float* wC = wpk + (rr * 3 + 2) * 27;
#pragma unroll
    for (int o = 0; o < 27; ++o) {
      K2[o] = __builtin_elementwise_fma(asf16x2(wA[o]), h01, K2[o]);
      K2[o] = __builtin_elementwise_fma(asf16x2(wB[o]), h12, K2[o]);
      K2[o] = __builtin_elementwise_fma(asf16x2(wC[o]), h23, K2[o]);
    }
  }

  // ---- boundary tap masks (x zero-pad semantics; kills bias too)
  const int od = d0 + wv, oh = h0 + ty, ow = w0 + 2 * tx;
#pragma unroll
  for (int o = 0; o < 27; ++o) {
    const int di = o / 9, dj = (o / 3) % 3, dk = o % 3;
    const bool mm = ((unsigned)(od + di - 1) < Dm) & ((unsigned)(oh + dj - 1) < Dm);
    const float m0 = (mm & ((unsigned)(ow + dk - 1) < Dm)) ? 1.f : 0.f;
    const float m1 = (mm & ((unsigned)(ow + dk)     < Dm)) ? 1.f : 0.f;
    K2[o] *= pkrtz(m0, m1);
  }

  const size_t obase = (((size_t)od) * Dm + oh) * Dm + ow;

  // ---- batch loop: per-wave pipeline, no barriers.
  // write staged b -> issue loads b+1 -> apply b (covers part of latency);
  // 8 blocks/CU x 4 waves = 32 independent streams hide the rest.
#pragma unroll 1
  for (int b = 0; b < Bn; ++b) {
#pragma unroll
    for (int k = 0; k < 5; ++k)
      sxw[64 * k + lane] = pkbits(nx[k].x, nx[k].y);

    const float* xb = x + (size_t)(b + 1 < Bn ? b + 1 : Bn - 1) * VOX;
#pragma unroll
    for (int k = 0; k < 5; ++k)
      nx[k] = *(const float2*)(xb + off[k]);

    f16x2 aA = {(__fp16)0.f, (__fp16)0.f};
    f16x2 aB = {(__fp16)0.f, (__fp16)0.f};
#pragma unroll
    for (int rr = 0; rr < 9; ++rr) {
      const int idx = ((rr / 3) * 10 + ty + (rr % 3)) * WR + tx;
      f16x2 a2 = asf16x2(sxw[idx]);
      f16x2 b2 = asf16x2(sxw[idx + 1]);
      f16x2 c2 = asf16x2(sxw[idx + 2]);
      f16x2 h01 = midpair(b2, a2);
      f16x2 h12 = b2;
      f16x2 h23 = midpair(c2, b2);
      if (rr & 1) {
        aB = __builtin_elementwise_fma(K2[rr * 3 + 0], h01, aB);
        aB = __builtin_elementwise_fma(K2[rr * 3 + 1], h12, aB);
        aB = __builtin_elementwise_fma(K2[rr * 3 + 2], h23, aB);
      } else {
        aA = __builtin_elementwise_fma(K2[rr * 3 + 0], h01, aA);
        aA = __builtin_elementwise_fma(K2[rr * 3 + 1], h12, aA);
        aA = __builtin_elementwise_fma(K2[rr * 3 + 2], h23, aA);
      }
    }
    f16x2 acc = aA + aB;
    float2 st; st.x = (float)acc.x; st.y = (float)acc.y;
    *(float2*)&out[(size_t)b * VOX + obase] = st;
  }
}

extern "C" void kernel_launch(void* const* d_in, const int* in_sizes, int n_in,
                              void* d_out, int out_size, void* d_ws, size_t ws_size,
                              hipStream_t stream) {
  const float* img = (const float*)d_in[0];
  const float* x   = (const float*)d_in[1];
  const float* Wf  = (const float*)d_in[2];
  const float* bf  = (const float*)d_in[3];
  float* out = (float*)d_out;
  float* wpk = (float*)d_ws;   // 756 floats: wpkT + bias, packed f16x2
  hipLaunchKernelGGL(packW, dim3(1), dim3(768), 0, stream, Wf, bf, wpk);
  // 4096 blocks = 8 blocks/CU x 256 CU x 2 full rounds
  hipLaunchKernelGGL(fused3d, dim3(4096), dim3(NT), 0, stream, img, x, wpk, out);
}

// Round 10
// 122.240 us; speedup vs baseline: 1.3601x; 1.3601x over previous
//
#include <hip/hip_runtime.h>

typedef __fp16 f16x2 __attribute__((ext_vector_type(2)));

#define Dm 128
#define Bn 16
#define VOX (Dm * Dm * Dm)
#define NT 256
#define WR 10            // words per halo row (20 halves: x[w0-2 .. w0+17])
#define SLAB 320         // 32 rows x 10 words per wave (rows 0..29 used)

__device__ __forceinline__ int iclamp(int v, int lo, int hi) {
  return v < lo ? lo : (v > hi ? hi : v);
}
__device__ __forceinline__ f16x2 pkrtz(float lo, float hi) {
  return __builtin_amdgcn_cvt_pkrtz(lo, hi);
}
__device__ __forceinline__ float pkbits(float lo, float hi) {
  return __builtin_bit_cast(float, __builtin_amdgcn_cvt_pkrtz(lo, hi));
}
__device__ __forceinline__ f16x2 asf16x2(float w) {
  return __builtin_bit_cast(f16x2, w);
}
// midpair(P, Q) = (Q.hi, P.lo)
__device__ __forceinline__ f16x2 midpair(f16x2 P, f16x2 Q) {
  unsigned r = __builtin_amdgcn_perm(__builtin_bit_cast(unsigned, P),
                                     __builtin_bit_cast(unsigned, Q),
                                     0x05040302u);
  return __builtin_bit_cast(f16x2, r);
}

// W transposed (wpkT[t*27+o] = W[o][t]) + bias, duplicated-half f16x2.
extern "C" __global__ void packW(const float* __restrict__ Wf,
                                 const float* __restrict__ bfp,
                                 float* __restrict__ wpk) {
  int i = threadIdx.x;
  if (i < 729) {
    int o = i / 27, t = i - o * 27;
    float v = Wf[i];
    wpk[t * 27 + o] = pkbits(v, v);
  } else if (i < 756) {
    float b = bfp[i - 729];
    wpk[i] = pkbits(b, b);
  }
}

__device__ __forceinline__ void load_batch(float2 nx[5], const float* xb,
                                           const int off[5]) {
#pragma unroll
  for (int k = 0; k < 5; ++k) nx[k] = *(const float2*)(xb + off[k]);
}
__device__ __forceinline__ void stage_lds(float* sxw, const float2 nx[5],
                                          int lane) {
#pragma unroll
  for (int k = 0; k < 5; ++k)
    sxw[64 * k + lane] = pkbits(nx[k].x, nx[k].y);
}
__device__ __forceinline__ f16x2 apply_tile(const float* sxw, const f16x2* K2,
                                            int ty, int tx) {
  f16x2 aA = {(__fp16)0.f, (__fp16)0.f};
  f16x2 aB = {(__fp16)0.f, (__fp16)0.f};
#pragma unroll
  for (int rr = 0; rr < 9; ++rr) {
    const int idx = ((rr / 3) * 10 + ty + (rr % 3)) * WR + tx;
    f16x2 a2 = asf16x2(sxw[idx]);
    f16x2 b2 = asf16x2(sxw[idx + 1]);
    f16x2 c2 = asf16x2(sxw[idx + 2]);
    f16x2 h01 = midpair(b2, a2);   // (x[w-1], x[w])
    f16x2 h12 = b2;                // (x[w],   x[w+1])
    f16x2 h23 = midpair(c2, b2);   // (x[w+1], x[w+2])
    if (rr & 1) {
      aB = __builtin_elementwise_fma(K2[rr * 3 + 0], h01, aB);
      aB = __builtin_elementwise_fma(K2[rr * 3 + 1], h12, aB);
      aB = __builtin_elementwise_fma(K2[rr * 3 + 2], h23, aB);
    } else {
      aA = __builtin_elementwise_fma(K2[rr * 3 + 0], h01, aA);
      aA = __builtin_elementwise_fma(K2[rr * 3 + 1], h12, aA);
      aA = __builtin_elementwise_fma(K2[rr * 3 + 2], h23, aA);
    }
  }
  return aA + aB;
}

// Wave-private tiles, ZERO barriers: each wave owns one z-slice (8y x 16w),
// stages its own 3z x 10y x 20w halo; waves are fully independent streams.
extern "C" __global__ void __launch_bounds__(NT, 4)   // VGPR cap 128: NO forced spill
fused3d(const float* __restrict__ img, const float* __restrict__ x,
        const float* __restrict__ wpk, float* __restrict__ out)
{
  __shared__ float sImg[4][SLAB];   // 5.1 KiB
  __shared__ float sX0[4][SLAB];    // 5.1 KiB  (even batches)
  __shared__ float sX1[4][SLAB];    // 5.1 KiB  (odd batches)

  const int tid  = threadIdx.x;
  const int lane = tid & 63;
  const int wv   = tid >> 6;       // wave id == z offset within block tile
  const int tx   = lane & 7;       // w-pair 0..7
  const int ty   = lane >> 3;      // h 0..7

  // T1 XCD swizzle: contiguous slab of 512 spatial tiles per XCD
  const int bid = blockIdx.x;
  const int s  = (bid & 7) * 512 + (bid >> 3);
  const int bx = s & 7, by = (s >> 3) & 15, bz = s >> 7;
  const int w0 = bx * 16, h0 = by * 8, d0 = bz * 4;

  // ---- staging map: word i = 64k+lane; row r=i/10 (zz=r/10, yy=r%10),
  // col c=i%10 -> aligned float2 at x[gd, gh, w0-2+2c]. Clamped; rows 30/31 pad.
  int off[5];
  float mk0[5], mk1[5];            // img zero-pad masks (conv SAME)
#pragma unroll
  for (int k = 0; k < 5; ++k) {
    int i  = 64 * k + lane;
    int r  = i / WR;
    int c  = i - r * WR;
    int zz = r / 10;
    int yy = r - zz * 10;
    int gdo = d0 + wv + zz - 1;
    int gho = h0 + yy - 1;
    int gwo = w0 - 2 + 2 * c;
    int gd = iclamp(gdo, 0, Dm - 1);
    int gh = iclamp(gho, 0, Dm - 1);
    int gw = iclamp(gwo, 0, Dm - 2);        // even bounds keep 8B alignment
    off[k] = (gd * Dm + gh) * Dm + gw;
    bool rk = ((unsigned)gdo < Dm) & ((unsigned)gho < Dm);
    mk0[k] = (rk & ((unsigned)gwo < Dm))       ? 1.f : 0.f;
    mk1[k] = (rk & ((unsigned)(gwo + 1) < Dm)) ? 1.f : 0.f;
  }

  float* simg = sImg[wv];
  float* sx0  = sX0[wv];
  float* sx1  = sX1[wv];

  // ---- issue batch-0 loads FIRST (K-gen ~1500cy covers their latency),
  // then stage img (zero-masked). No barriers anywhere (wave-private LDS).
  float2 nxA[5], nxB[5];
  load_batch(nxA, x, off);
#pragma unroll
  for (int k = 0; k < 5; ++k) {
    float2 v = *(const float2*)(img + off[k]);
    simg[64 * k + lane] = pkbits(v.x * mk0[k], v.y * mk1[k]);
  }

  // ---- K-gen: single pass, packed fp16; W rows contiguous (wpkT s_loads)
  f16x2 K2[27];
#pragma unroll
  for (int o = 0; o < 27; ++o) K2[o] = asf16x2(wpk[729 + o]);
#pragma unroll
  for (int rr = 0; rr < 9; ++rr) {
    const int idx = ((rr / 3) * 10 + ty + (rr % 3)) * WR + tx;
    f16x2 a2 = asf16x2(simg[idx]);
    f16x2 b2 = asf16x2(simg[idx + 1]);
    f16x2 c2 = asf16x2(simg[idx + 2]);
    f16x2 h01 = midpair(b2, a2);
    f16x2 h12 = b2;
    f16x2 h23 = midpair(c2, b2);
    const float* wA = wpk + (rr * 3 + 0) * 27;
    const float* wB = wpk + (rr * 3 + 1) * 27;
    const float* wC = wpk + (rr * 3 + 2) * 27;
#pragma unroll
    for (int o = 0; o < 27; ++o) {
      K2[o] = __builtin_elementwise_fma(asf16x2(wA[o]), h01, K2[o]);
      K2[o] = __builtin_elementwise_fma(asf16x2(wB[o]), h12, K2[o]);
      K2[o] = __builtin_elementwise_fma(asf16x2(wC[o]), h23, K2[o]);
    }
  }

  // ---- boundary tap masks (x zero-pad semantics; kills bias too)
  const int od = d0 + wv, oh = h0 + ty, ow = w0 + 2 * tx;
#pragma unroll
  for (int o = 0; o < 27; ++o) {
    const int di = o / 9, dj = (o / 3) % 3, dk = o % 3;
    const bool mm = ((unsigned)(od + di - 1) < Dm) & ((unsigned)(oh + dj - 1) < Dm);
    const float m0 = (mm & ((unsigned)(ow + dk - 1) < Dm)) ? 1.f : 0.f;
    const float m1 = (mm & ((unsigned)(ow + dk)     < Dm)) ? 1.f : 0.f;
    K2[o] *= pkrtz(m0, m1);
  }

  const size_t obase = (((size_t)od) * Dm + oh) * Dm + ow;

  // ---- batch loop: unroll-by-2, static nxA/nxB + LDS dbuf, no barriers.
  // Per half: stage b -> issue loads b+1 -> apply b (covers load latency);
  // independent waves' residual stalls interleave on the SIMD.
#pragma unroll 1
  for (int bb = 0; bb < Bn; bb += 2) {
    stage_lds(sx0, nxA, lane);
    load_batch(nxB, x + (size_t)(bb + 1) * VOX, off);
    {
      f16x2 acc = apply_tile(sx0, K2, ty, tx);
      float2 st; st.x = (float)acc.x; st.y = (float)acc.y;
      *(float2*)&out[(size_t)bb * VOX + obase] = st;
    }
    stage_lds(sx1, nxB, lane);
    if (bb + 2 < Bn) load_batch(nxA, x + (size_t)(bb + 2) * VOX, off);
    {
      f16x2 acc = apply_tile(sx1, K2, ty, tx);
      float2 st; st.x = (float)acc.x; st.y = (float)acc.y;
      *(float2*)&out[(size_t)(bb + 1) * VOX + obase] = st;
    }
  }
}

extern "C" void kernel_launch(void* const* d_in, const int* in_sizes, int n_in,
                              void* d_out, int out_size, void* d_ws, size_t ws_size,
                              hipStream_t stream) {
  const float* img = (const float*)d_in[0];
  const float* x   = (const float*)d_in[1];
  const float* Wf  = (const float*)d_in[2];
  const float* bf  = (const float*)d_in[3];
  float* out = (float*)d_out;
  float* wpk = (float*)d_ws;   // 756 floats: wpkT + bias, packed f16x2
  hipLaunchKernelGGL(packW, dim3(1), dim3(768), 0, stream, Wf, bf, wpk);
  hipLaunchKernelGGL(fused3d, dim3(4096), dim3(NT), 0, stream, img, x, wpk, out);
}